// Round 4
// baseline (141.957 us; speedup 1.0000x reference)
//
#include <hip/hip_runtime.h>

// CenterLossForward:
//   loss        = LAMBDA/BATCH * sum_b ||batch_b - centers[y_b]||^2
//   new_centers = centers; new_centers[y_b] += ALPHA*(batch_b - centers[y_b])  (dups accumulate)
// d_out layout: [loss (1 float)] [new_centers (NUM_CLASSES*EMBED floats)]
//
// R4: bulk copy with aligned 16B stores + HW-unaligned (4B-aligned) 16B loads.
// gfx950 supports unaligned global access natively — no shfl realignment.

constexpr int   NUM_CLASSES = 100000;
constexpr int   EMBED       = 512;
constexpr int   BATCH       = 4096;
constexpr float LAMBDA      = 0.01f;
constexpr float ALPHA       = 0.1f;

constexpr long  NFLOAT = (long)NUM_CLASSES * EMBED;   // 51,200,000
constexpr long  NGRP   = (NFLOAT - 3) / 4;            // 12,799,999 aligned dst float4 groups

typedef float float4_u __attribute__((ext_vector_type(4), aligned(4)));
typedef float float4_a __attribute__((ext_vector_type(4), aligned(16)));

__global__ void link_kernel(const int* __restrict__ y, int* __restrict__ head,
                            int* __restrict__ nxt) {
    int s = blockIdx.x * blockDim.x + threadIdx.x;
    if (s < BATCH) nxt[s] = atomicExch(&head[y[s]], s);
}

// dst4[1+g] (aligned, covers out floats 4+4g..7+4g = new_centers 3+4g..6+4g)
//   = unaligned load src[3+4g .. 6+4g]
__global__ void __launch_bounds__(256) copy_unaligned_kernel(
        const float* __restrict__ src, float* __restrict__ dst) {
    const long tid = (long)blockIdx.x * blockDim.x + threadIdx.x;
    const long nth = (long)gridDim.x * blockDim.x;
    float4_a* dst4 = (float4_a*)dst;

    for (long g = tid; g < NGRP; g += nth) {
        float4_u v = *(const float4_u*)(src + 3 + 4 * g);
        dst4[1 + g] = (float4_a){v.x, v.y, v.z, v.w};
    }

    if (tid == 0) {
        dst[1] = src[0];
        dst[2] = src[1];
        dst[3] = src[2];
        dst[NFLOAT] = src[NFLOAT - 1];
    }
}

// Rewrite touched rows + loss. Runs after copy; its stores win WAW.
__global__ void __launch_bounds__(256) update_rows_kernel(
        const float* __restrict__ batch,
        const float* __restrict__ centers,
        const int* __restrict__ head,
        const int* __restrict__ nxt,
        float* __restrict__ out) {
    const int lane = threadIdx.x & 63;
    const int wid  = threadIdx.x >> 6;
    const int gw   = blockIdx.x * 4 + wid;
    const int nw   = gridDim.x * 4;

    float lacc = 0.f;
    for (int r = gw; r < NUM_CLASSES; r += nw) {
        int s = head[r];                       // wave-uniform
        if (s < 0) continue;

        const float* crow = centers + (size_t)r * EMBED;
        float c[8], a[8];
        #pragma unroll
        for (int k = 0; k < 8; ++k) { c[k] = crow[lane + 64 * k]; a[k] = 0.f; }

        while (s >= 0) {
            const float* brow = batch + (size_t)s * EMBED;
            #pragma unroll
            for (int k = 0; k < 8; ++k) {
                float d = brow[lane + 64 * k] - c[k];
                a[k] += d;
                lacc += d * d;
            }
            s = nxt[s];
        }

        float* orow = out + 1 + (size_t)r * EMBED;
        #pragma unroll
        for (int k = 0; k < 8; ++k) orow[lane + 64 * k] = c[k] + ALPHA * a[k];
    }

    #pragma unroll
    for (int off = 32; off > 0; off >>= 1) lacc += __shfl_xor(lacc, off, 64);
    if (lane == 0 && lacc != 0.f) atomicAdd(out, lacc * (LAMBDA / (float)BATCH));
}

// ---- fallback (ws too small): blit + per-sample atomics ----
__global__ void center_update_fallback(const int* __restrict__ y,
                                       const float4* __restrict__ batch,
                                       const float4* __restrict__ centers,
                                       float* __restrict__ out) {
    const int b = blockIdx.x, t = threadIdx.x;
    const int cls = y[b];
    const float4 xb = batch[(size_t)b * (EMBED / 4) + t];
    const float4 c  = centers[(size_t)cls * (EMBED / 4) + t];
    const float dx = xb.x - c.x, dy = xb.y - c.y, dz = xb.z - c.z, dw = xb.w - c.w;
    float* orow = out + 1 + (size_t)cls * EMBED + (size_t)t * 4;
    atomicAdd(orow + 0, ALPHA * dx);
    atomicAdd(orow + 1, ALPHA * dy);
    atomicAdd(orow + 2, ALPHA * dz);
    atomicAdd(orow + 3, ALPHA * dw);
    float s = dx * dx + dy * dy + dz * dz + dw * dw;
    #pragma unroll
    for (int off = 32; off > 0; off >>= 1) s += __shfl_down(s, off, 64);
    __shared__ float wsum[2];
    const int lane = t & 63, wid = t >> 6;
    if (lane == 0) wsum[wid] = s;
    __syncthreads();
    if (t == 0) atomicAdd(out, (wsum[0] + wsum[1]) * (LAMBDA / (float)BATCH));
}

extern "C" void kernel_launch(void* const* d_in, const int* in_sizes, int n_in,
                              void* d_out, int out_size, void* d_ws, size_t ws_size,
                              hipStream_t stream) {
    const int*   y       = (const int*)d_in[0];
    const float* batch   = (const float*)d_in[1];
    const float* centers = (const float*)d_in[2];
    float*       out     = (float*)d_out;

    const size_t head_bytes = (size_t)NUM_CLASSES * sizeof(int);
    const size_t next_bytes = (size_t)BATCH * sizeof(int);

    hipMemsetAsync(out, 0, sizeof(float), stream);  // loss accumulator

    if (ws_size >= head_bytes + next_bytes) {
        int* head = (int*)d_ws;
        int* nxt  = (int*)((char*)d_ws + head_bytes);

        hipMemsetAsync(head, 0xFF, head_bytes, stream);
        link_kernel<<<(BATCH + 255) / 256, 256, 0, stream>>>(y, head, nxt);
        copy_unaligned_kernel<<<2048, 256, 0, stream>>>(centers, out);
        update_rows_kernel<<<1024, 256, 0, stream>>>(batch, centers, head, nxt, out);
    } else {
        hipMemcpyAsync(out + 1, centers, NFLOAT * sizeof(float),
                       hipMemcpyDeviceToDevice, stream);
        center_update_fallback<<<BATCH, EMBED / 4, 0, stream>>>(
            y, (const float4*)batch, (const float4*)centers, out);
    }
}

// Round 6
// 118.458 us; speedup vs baseline: 1.1984x; 1.1984x over previous
//
#include <hip/hip_runtime.h>

// CenterLossForward:
//   loss        = LAMBDA/BATCH * sum_b ||batch_b - centers[y_b]||^2
//   new_centers = centers; new_centers[y_b] += ALPHA*(batch_b - centers[y_b])  (dups accumulate)
// d_out layout: [loss (1 float)] [new_centers (NUM_CLASSES*EMBED floats)]
//
// R6: R3's aligned-both-sides shfl-realign copy + NON-TEMPORAL stores (via
// native ext_vector_type, which __builtin_nontemporal_store accepts) so the
// 205MB write stream doesn't evict centers (204.8MB, L3-resident across
// replays) -> read side becomes L3 hits, write side streams at ~7 TB/s.

constexpr int   NUM_CLASSES = 100000;
constexpr int   EMBED       = 512;
constexpr int   BATCH       = 4096;
constexpr float LAMBDA      = 0.01f;
constexpr float ALPHA       = 0.1f;

constexpr long  NFLOAT = (long)NUM_CLASSES * EMBED;   // 51,200,000
constexpr long  NGRP   = (NFLOAT - 3) / 4;            // 12,799,999 full dst float4 groups
constexpr long  NSRC4  = NFLOAT / 4;                  // 12,800,000 src float4 words

typedef float f4 __attribute__((ext_vector_type(4)));

__global__ void link_kernel(const int* __restrict__ y, int* __restrict__ head,
                            int* __restrict__ nxt) {
    int s = blockIdx.x * blockDim.x + threadIdx.x;
    if (s < BATCH) nxt[s] = atomicExch(&head[y[s]], s);
}

// Aligned-both-sides shifted copy: dst4[1+g] = {src[4g+3] .. src[4g+6]}
// Stores are non-temporal (bypass cache allocation on the write stream).
__global__ void __launch_bounds__(256) copy_shift_kernel(
        const f4* __restrict__ src4, f4* __restrict__ dst4,
        const float* __restrict__ src, float* __restrict__ dst) {
    const int  lane = threadIdx.x & 63;
    const long gw   = (long)((blockIdx.x * blockDim.x + threadIdx.x) >> 6);
    const long nw   = (long)((gridDim.x * blockDim.x) >> 6);

    for (long base = gw * 64; base < NGRP; base += nw * 64) {
        const long g  = base + lane;
        f4 v = (g < NSRC4) ? src4[g] : (f4){0.f, 0.f, 0.f, 0.f};

        f4 vn;
        vn.x = __shfl_down(v.x, 1, 64);
        vn.y = __shfl_down(v.y, 1, 64);
        vn.z = __shfl_down(v.z, 1, 64);
        vn.w = __shfl_down(v.w, 1, 64);
        if (lane == 63 && g + 1 < NSRC4) vn = src4[g + 1];

        if (g < NGRP) {
            f4 o = {v.w, vn.x, vn.y, vn.z};
            __builtin_nontemporal_store(o, &dst4[1 + g]);
        }
    }

    // edges: new_centers floats 0,1,2 and the final float
    if (blockIdx.x == 0 && threadIdx.x == 0) {
        dst[1] = src[0];
        dst[2] = src[1];
        dst[3] = src[2];
        dst[NFLOAT] = src[NFLOAT - 1];
    }
}

// Rewrite touched rows + loss. Runs AFTER copy (same stream) so its row
// stores win the write-after-write.
__global__ void __launch_bounds__(256) update_rows_kernel(
        const float* __restrict__ batch,
        const float* __restrict__ centers,
        const int* __restrict__ head,
        const int* __restrict__ nxt,
        float* __restrict__ out) {
    const int lane = threadIdx.x & 63;
    const int wid  = threadIdx.x >> 6;
    const int gw   = blockIdx.x * 4 + wid;
    const int nw   = gridDim.x * 4;

    float lacc = 0.f;
    for (int r = gw; r < NUM_CLASSES; r += nw) {
        int s = head[r];                       // wave-uniform
        if (s < 0) continue;

        const float* crow = centers + (size_t)r * EMBED;
        float c[8], a[8];
        #pragma unroll
        for (int k = 0; k < 8; ++k) { c[k] = crow[lane + 64 * k]; a[k] = 0.f; }

        while (s >= 0) {
            const float* brow = batch + (size_t)s * EMBED;
            #pragma unroll
            for (int k = 0; k < 8; ++k) {
                float d = brow[lane + 64 * k] - c[k];
                a[k] += d;
                lacc += d * d;
            }
            s = nxt[s];
        }

        float* orow = out + 1 + (size_t)r * EMBED;
        #pragma unroll
        for (int k = 0; k < 8; ++k) orow[lane + 64 * k] = c[k] + ALPHA * a[k];
    }

    #pragma unroll
    for (int off = 32; off > 0; off >>= 1) lacc += __shfl_xor(lacc, off, 64);
    if (lane == 0 && lacc != 0.f) atomicAdd(out, lacc * (LAMBDA / (float)BATCH));
}

// ---- fallback (ws too small): blit + per-sample atomics ----
__global__ void center_update_fallback(const int* __restrict__ y,
                                       const float4* __restrict__ batch,
                                       const float4* __restrict__ centers,
                                       float* __restrict__ out) {
    const int b = blockIdx.x, t = threadIdx.x;
    const int cls = y[b];
    const float4 xb = batch[(size_t)b * (EMBED / 4) + t];
    const float4 c  = centers[(size_t)cls * (EMBED / 4) + t];
    const float dx = xb.x - c.x, dy = xb.y - c.y, dz = xb.z - c.z, dw = xb.w - c.w;
    float* orow = out + 1 + (size_t)cls * EMBED + (size_t)t * 4;
    atomicAdd(orow + 0, ALPHA * dx);
    atomicAdd(orow + 1, ALPHA * dy);
    atomicAdd(orow + 2, ALPHA * dz);
    atomicAdd(orow + 3, ALPHA * dw);
    float s = dx * dx + dy * dy + dz * dz + dw * dw;
    #pragma unroll
    for (int off = 32; off > 0; off >>= 1) s += __shfl_down(s, off, 64);
    __shared__ float wsum[2];
    const int lane = t & 63, wid = t >> 6;
    if (lane == 0) wsum[wid] = s;
    __syncthreads();
    if (t == 0) atomicAdd(out, (wsum[0] + wsum[1]) * (LAMBDA / (float)BATCH));
}

extern "C" void kernel_launch(void* const* d_in, const int* in_sizes, int n_in,
                              void* d_out, int out_size, void* d_ws, size_t ws_size,
                              hipStream_t stream) {
    const int*   y       = (const int*)d_in[0];
    const float* batch   = (const float*)d_in[1];
    const float* centers = (const float*)d_in[2];
    float*       out     = (float*)d_out;

    const size_t head_bytes = (size_t)NUM_CLASSES * sizeof(int);
    const size_t next_bytes = (size_t)BATCH * sizeof(int);

    (void)hipMemsetAsync(out, 0, sizeof(float), stream);  // loss accumulator

    if (ws_size >= head_bytes + next_bytes) {
        int* head = (int*)d_ws;
        int* nxt  = (int*)((char*)d_ws + head_bytes);

        (void)hipMemsetAsync(head, 0xFF, head_bytes, stream);
        link_kernel<<<(BATCH + 255) / 256, 256, 0, stream>>>(y, head, nxt);
        copy_shift_kernel<<<2048, 256, 0, stream>>>(
            (const f4*)centers, (f4*)out, centers, out);
        update_rows_kernel<<<1024, 256, 0, stream>>>(batch, centers, head, nxt, out);
    } else {
        (void)hipMemcpyAsync(out + 1, centers, NFLOAT * sizeof(float),
                             hipMemcpyDeviceToDevice, stream);
        center_update_fallback<<<BATCH, EMBED / 4, 0, stream>>>(
            y, (const float4*)batch, (const float4*)centers, out);
    }
}